// Round 16
// baseline (307.515 us; speedup 1.0000x reference)
//
#include <hip/hip_runtime.h>
#include <math.h>

#define BB 16
#define CC 64
#define NN 2048
#define KK 8
#define CAND 16          // phase-1 candidates (exact top-8 subset; validated R3/R6/R7/R10-R15)
#define QB 4             // queries per block (one per wave); keys LDS = QB*NN*4 = 32 KB
#define NT (QB * 64)     // 256 threads
#define MPW (NN / QB)    // 512 m-points per wave
#define DPL 32           // keys per lane

typedef float floatx2 __attribute__((ext_vector_type(2)));
typedef unsigned long long u64;

// order-preserving fp32 -> u32 flip: ascending uint == ascending float
__device__ __forceinline__ unsigned ordflip(float f) {
    unsigned u = __float_as_uint(f);
    return u ^ ((u & 0x80000000u) ? 0xFFFFFFFFu : 0x80000000u);
}
// inverse (on the masked high bits): recover approximate r from a packed key
__device__ __forceinline__ float unflip(unsigned k) {
    unsigned u = k & 0xFFFFF800u;
    u ^= (u & 0x80000000u) ? 0x80000000u : 0xFFFFFFFFu;
    return __uint_as_float(u);
}

// ---- cross-lane helpers: DPP for offsets inside a 16-lane row, bpermute beyond ----
template<int C>
__device__ __forceinline__ unsigned dppu(unsigned v) {
    return (unsigned)__builtin_amdgcn_update_dpp(0, (int)v, C, 0xF, 0xF, true);
}
template<int OFF>
__device__ __forceinline__ unsigned shx(unsigned v) {
    if constexpr (OFF == 1)       return dppu<0xB1>(v);    // quad_perm xor 1
    else if constexpr (OFF == 2)  return dppu<0x4E>(v);    // quad_perm xor 2
    else if constexpr (OFF == 7)  return dppu<0x141>(v);   // row_half_mirror = xor 7
    else if constexpr (OFF == 15) return dppu<0x140>(v);   // row_mirror      = xor 15
    else return (unsigned)__shfl_xor((int)v, OFF, 64);
}
template<int C>
__device__ __forceinline__ double dppd(double v) {
    unsigned long long u = (unsigned long long)__double_as_longlong(v);
    int lo = __builtin_amdgcn_update_dpp(0, (int)(u & 0xffffffffull), C, 0xF, 0xF, true);
    int hi = __builtin_amdgcn_update_dpp(0, (int)(u >> 32),           C, 0xF, 0xF, true);
    return __longlong_as_double((long long)(((unsigned long long)(unsigned)hi << 32) | (unsigned)lo));
}

// ascending bitonic cleanup of a bitonic 16-sequence (j = 8,4,2,1)
__device__ __forceinline__ void clean16(unsigned k[CAND]) {
#define CMPEX(a_, b_) { unsigned lo = k[a_] < k[b_] ? k[a_] : k[b_]; \
                        unsigned hi = k[a_] < k[b_] ? k[b_] : k[a_]; k[a_] = lo; k[b_] = hi; }
    CMPEX(0,8) CMPEX(1,9) CMPEX(2,10) CMPEX(3,11) CMPEX(4,12) CMPEX(5,13) CMPEX(6,14) CMPEX(7,15)
    CMPEX(0,4) CMPEX(1,5) CMPEX(2,6)  CMPEX(3,7)  CMPEX(8,12) CMPEX(9,13) CMPEX(10,14) CMPEX(11,15)
    CMPEX(0,2) CMPEX(1,3) CMPEX(4,6)  CMPEX(5,7)  CMPEX(8,10) CMPEX(9,11) CMPEX(12,14) CMPEX(13,15)
    CMPEX(0,1) CMPEX(2,3) CMPEX(4,5)  CMPEX(6,7)  CMPEX(8,9)  CMPEX(10,11) CMPEX(12,13) CMPEX(14,15)
#undef CMPEX
}

// one butterfly merge step: my sorted-16 vs partner's sorted-16 -> top-16 of union, sorted
template<int OFF>
__device__ __forceinline__ void merge16(unsigned k[CAND]) {
    unsigned pk[CAND];
#pragma unroll
    for (int j = 0; j < CAND; ++j) pk[j] = shx<OFF>(k[j]);
#pragma unroll
    for (int j = 0; j < CAND; ++j) {
        unsigned b2_ = pk[CAND - 1 - j];
        k[j] = (k[j] < b2_) ? k[j] : b2_;
    }
    clean16(k);
}

// xx[b,n] = sum_c x[b,c,n]^2  (fp32 proxy only — phase 2 rescores exactly when needed)
__global__ __launch_bounds__(256) void compute_xx(const float* __restrict__ x,
                                                  float* __restrict__ xx) {
    int t = blockIdx.x * 256 + threadIdx.x;      // t in [0, B*N)
    int b = t >> 11, n = t & (NN - 1);
    const float* xb = x + b * (CC * NN) + n;
    float s = 0.f;
#pragma unroll
    for (int c = 0; c < CC; ++c) { float v = xb[c * NN]; s = fmaf(v, v, s); }
    xx[t] = s;
}

// (NT,4): VGPR cap 128 — room for 4 prefetch buffers (48 regs) + 32 accumulators.
// R13-R15 showed the compiler schedules load->use tightly (VGPR ~50, VALUBusy ~49%,
// ~50% stall on ~200-cyc L2 hits). Parity-indexed buffers with depth-2 prefetch force
// each load to be issued ~2 iterations (~90 cyc own-wave + cross-wave overlap) early,
// with ZERO copies (R14's rotation added 12 v_mov/iter and regressed).
__global__ __launch_bounds__(NT, 4) void knn_upsample(const float* __restrict__ x,
                                                      const float* __restrict__ xxg,
                                                      float* __restrict__ out) {
    __shared__ unsigned keys[QB][NN];   // 32 KB

    const int tid  = threadIdx.x;
    const int w    = tid >> 6;                 // wave id = query id within block
    const int lane = tid & 63;
    const int blk  = blockIdx.x;

    // XCD-aware batch affinity (R13, measured: HBM fetch 38 MB -> 4.5 MB): blocks go
    // round-robin to 8 XCDs (blk % 8, m09); pin XCD x to batches {2x, 2x+1} so the
    // per-XCD phase-A working set is 1 MB (L2-resident) instead of 8 MB.
    const int xcd = blk & 7;
    const int j   = blk >> 3;                  // [0, 1024)
    const int b   = 2 * xcd + (j >> 9);        // batch
    const int n0  = (j & 511) << 2;            // 4 consecutive queries per block
    const float* xb = x + b * (CC * NN);

    // ---------------- phase A: inner products; wave w covers 512 m-points for ALL 4 queries ----------------
    const int mbase = w * MPW + 4 * lane;      // points mbase..mbase+3 and mbase+256..+259
    floatx2 acc[QB][4];                        // [query][pt-pair]
#pragma unroll
    for (int q2 = 0; q2 < QB; ++q2)
#pragma unroll
        for (int g = 0; g < 4; ++g) acc[q2][g] = (floatx2){0.f, 0.f};

    const float* base0 = xb + mbase;
    const float* base1 = xb + mbase + 256;
    const float* baseq = xb + n0;

    // depth-2 software pipeline with 4 parity buffers (indices constant after unroll
    // -> distinct registers, no v_mov). Load c+2 while computing c.
    float4 X0[4], X1[4], QA[4];
    X0[0] = *(const float4*)(base0);           X0[1] = *(const float4*)(base0 + NN);
    X1[0] = *(const float4*)(base1);           X1[1] = *(const float4*)(base1 + NN);
    QA[0] = *(const float4*)(baseq);           QA[1] = *(const float4*)(baseq + NN);

#pragma unroll
    for (int c = 0; c < CC; ++c) {
        const int pb = c & 3;
        if (c + 2 < CC) {
            const int nb = (c + 2) & 3;
            X0[nb] = *(const float4*)(base0 + (c + 2) * NN);
            X1[nb] = *(const float4*)(base1 + (c + 2) * NN);
            QA[nb] = *(const float4*)(baseq + (c + 2) * NN);
        }
        const floatx2 x0 = {X0[pb].x, X0[pb].y}, x1 = {X0[pb].z, X0[pb].w};
        const floatx2 x2 = {X1[pb].x, X1[pb].y}, x3 = {X1[pb].z, X1[pb].w};
        const float qv[QB] = {QA[pb].x, QA[pb].y, QA[pb].z, QA[pb].w};
#pragma unroll
        for (int q2 = 0; q2 < QB; ++q2) {
            const floatx2 qq = {qv[q2], qv[q2]};
            acc[q2][0] = x0 * qq + acc[q2][0];   // v_pk_fma_f32
            acc[q2][1] = x1 * qq + acc[q2][1];
            acc[q2][2] = x2 * qq + acc[q2][2];
            acc[q2][3] = x3 * qq + acc[q2][3];
        }
    }

    // epilogue: r = xx_m - 2*I -> packed u32 key (idx in low 11 bits) -> LDS
    {
        const float4 xxv0 = *(const float4*)(xxg + b * NN + mbase);
        const float4 xxv1 = *(const float4*)(xxg + b * NN + mbase + 256);
        const float xxa[8] = {xxv0.x, xxv0.y, xxv0.z, xxv0.w, xxv1.x, xxv1.y, xxv1.z, xxv1.w};
#pragma unroll
        for (int q2 = 0; q2 < QB; ++q2) {
            const int nq = n0 + q2;
            unsigned kk[8];
#pragma unroll
            for (int p = 0; p < 8; ++p) {
                const int g = p >> 1;
                float I = (p & 1) ? acc[q2][g].y : acc[q2][g].x;
                float r = fmaf(-2.f, I, xxa[p]);
                const int m = mbase + ((p < 4) ? p : (252 + p));   // +0..3 or +256..259
                unsigned key = (ordflip(r) & 0xFFFFF800u) | (unsigned)m;
                kk[p] = (m == nq) ? 0xFFFFFFFFu : key;             // exclude self
            }
            *(uint4*)(&keys[q2][mbase])       = make_uint4(kk[0], kk[1], kk[2], kk[3]);
            *(uint4*)(&keys[q2][mbase + 256]) = make_uint4(kk[4], kk[5], kk[6], kk[7]);
        }
    }
    __syncthreads();

    // ---------------- phase B: wave w selects candidates for query n = n0 + w ----------------
    const int n = n0 + w;
    unsigned key[DPL];
#pragma unroll
    for (int t = 0; t < 8; ++t) {              // contiguous uint4 reads (ds_read_b128)
        uint4 kv = *(const uint4*)(&keys[w][256 * t + 4 * lane]);
        key[4 * t] = kv.x; key[4 * t + 1] = kv.y; key[4 * t + 2] = kv.z; key[4 * t + 3] = kv.w;
    }

    // per-lane TOP-8-of-32: 4 bitonic sort-8 (asc,desc,asc,desc), discard-merge pairs,
    // final discard-merge. P(lane holds >8 of wave top-16) ~ 4e-11/query — safe.
#pragma unroll
    for (int blk4 = 0; blk4 < 4; ++blk4) {
        const int base = blk4 * 8;
        const bool asc = (blk4 & 1) == 0;
#pragma unroll
        for (int k = 2; k <= 8; k <<= 1) {
#pragma unroll
            for (int jj = k >> 1; jj > 0; jj >>= 1) {
#pragma unroll
                for (int i = 0; i < 8; ++i) {
                    int l = i ^ jj;
                    if (l > i) {
                        bool up = (((i & k) == 0) == asc);
                        unsigned a = key[base + i], b2_ = key[base + l];
                        unsigned lo = a < b2_ ? a : b2_, hi = a < b2_ ? b2_ : a;
                        key[base + i] = up ? lo : hi;
                        key[base + l] = up ? hi : lo;
                    }
                }
            }
        }
    }
#pragma unroll
    for (int i = 0; i < 8; ++i) key[i] = key[i] < key[8 + i] ? key[i] : key[8 + i];
#pragma unroll
    for (int jj = 4; jj > 0; jj >>= 1)
#pragma unroll
        for (int i = 0; i < 8; ++i) {
            int l = i ^ jj;
            if (l > i && key[l] < key[i]) { unsigned t2 = key[i]; key[i] = key[l]; key[l] = t2; }
        }
#pragma unroll
    for (int i = 0; i < 8; ++i) key[16 + i] = key[16 + i] < key[24 + i] ? key[16 + i] : key[24 + i];
#pragma unroll
    for (int jj = 4; jj > 0; jj >>= 1)
#pragma unroll
        for (int i = 0; i < 8; ++i) {
            int l = i ^ jj;
            if (l > i && key[16 + l] < key[16 + i]) { unsigned t2 = key[16 + i]; key[16 + i] = key[16 + l]; key[16 + l] = t2; }
        }
#pragma unroll
    for (int i = 0; i < 8; ++i) key[i] = key[i] < key[16 + 7 - i] ? key[i] : key[16 + 7 - i];
#pragma unroll
    for (int jj = 4; jj > 0; jj >>= 1)
#pragma unroll
        for (int i = 0; i < 8; ++i) {
            int l = i ^ jj;
            if (l > i && key[l] < key[i]) { unsigned t2 = key[i]; key[i] = key[l]; key[l] = t2; }
        }

    // butterfly step 1 (xor 1, DPP): my-8 ++ reversed partner-8 = bitonic 16 -> sorted 16
    unsigned k16[CAND];
    {
        unsigned p8[8];
#pragma unroll
        for (int jj = 0; jj < 8; ++jj) p8[jj] = shx<1>(key[jj]);
#pragma unroll
        for (int jj = 0; jj < 8; ++jj) { k16[jj] = key[jj]; k16[8 + jj] = p8[7 - jj]; }
        clean16(k16);
    }
    merge16<2>(k16);
    merge16<7>(k16);
    merge16<15>(k16);
    merge16<16>(k16);
    merge16<32>(k16);

    // extract indices; belt-and-braces lane-0 broadcast (unique keys guarantee uniformity)
    int i16[CAND];
#pragma unroll
    for (int jj = 0; jj < CAND; ++jj) i16[jj] = __shfl((int)(k16[jj] & 0x7FFu), 0, 64);

    // ---------------- gap test: can the proxy alone certify the top-8 SET? ----------------
    const float r7 = unflip(k16[7]), r8 = unflip(k16[8]);
    const float eps = fmaxf(fabsf(r7), fabsf(r8)) * 0.0009765625f + 2e-3f;  // 2^-10 rel + abs floor
    float ssum = 0.f;

    if (r8 - r7 > eps) {
        // ---- fast path: proxy top-8 is exact; 8 gathers + sum ----
#pragma unroll
        for (int jj = 0; jj < KK; ++jj) ssum += xb[lane * NN + i16[jj]];
    } else {
        // ---- slow path: exact fp64 rescore -> u64 keys -> pairwise rank ----
        const double qd = (double)xb[lane * NN + n];   // lane = channel
        u64 ke[CAND];
        float xf[CAND];
#pragma unroll
        for (int jj = 0; jj < CAND; ++jj) {
            const float xv = xb[lane * NN + i16[jj]];
            xf[jj] = xv;
            double dt = (double)xv - qd;
            double part = dt * dt;
            part += dppd<0xB1>(part);
            part += dppd<0x4E>(part);
            part += dppd<0x141>(part);
            part += dppd<0x140>(part);
            part += __shfl_xor(part, 16, 64);
            part += __shfl_xor(part, 32, 64);
            u64 eb = (u64)__double_as_longlong(part);  // identical on all lanes, >= 0
            ke[jj] = (eb & ~2047ull) | (u64)(unsigned)i16[jj];
        }
        int rank[CAND];
#pragma unroll
        for (int jj = 0; jj < CAND; ++jj) rank[jj] = 0;
#pragma unroll
        for (int jj = 0; jj < CAND; ++jj)
#pragma unroll
            for (int k2 = jj + 1; k2 < CAND; ++k2) {
                const bool jw = ke[jj] < ke[k2];
                rank[k2] += jw ? 1 : 0;
                rank[jj] += jw ? 0 : 1;
            }
#pragma unroll
        for (int jj = 0; jj < CAND; ++jj) ssum += (rank[jj] < KK) ? xf[jj] : 0.f;
    }

    float mean = ssum * 0.125f;
    float* ob = out + b * (CC * 2 * NN) + lane * (2 * NN);
    ob[n]      = xb[lane * NN + n];   // first half: copy of x
    ob[NN + n] = mean;                // second half: mean of exact 8-NN features
}

extern "C" void kernel_launch(void* const* d_in, const int* in_sizes, int n_in,
                              void* d_out, int out_size, void* d_ws, size_t ws_size,
                              hipStream_t stream) {
    (void)in_sizes; (void)n_in; (void)ws_size; (void)out_size;
    const float* x = (const float*)d_in[0];
    float* xx = (float*)d_ws;                 // B*N floats = 128 KB scratch
    float* out = (float*)d_out;
    compute_xx<<<dim3(BB * NN / 256), dim3(256), 0, stream>>>(x, xx);
    knn_upsample<<<dim3(BB * NN / QB), dim3(NT), 0, stream>>>(x, xx, out);
}

// Round 17
// 306.440 us; speedup vs baseline: 1.0035x; 1.0035x over previous
//
#include <hip/hip_runtime.h>
#include <math.h>

#define BB 16
#define CC 64
#define NN 2048
#define KK 8
#define CAND 16          // phase-1 candidates (exact top-8 subset; validated R3/R6/R7/R10-R16)
#define QB 4             // queries per block (one per wave); keys LDS = QB*NN*4 = 32 KB
#define NT (QB * 64)     // 256 threads
#define MPW (NN / QB)    // 512 m-points per wave
#define DPL 32           // keys per lane

typedef float floatx2 __attribute__((ext_vector_type(2)));
typedef unsigned long long u64;

// order-preserving fp32 -> u32 flip: ascending uint == ascending float
__device__ __forceinline__ unsigned ordflip(float f) {
    unsigned u = __float_as_uint(f);
    return u ^ ((u & 0x80000000u) ? 0xFFFFFFFFu : 0x80000000u);
}
// inverse (on the masked high bits): recover approximate r from a packed key
__device__ __forceinline__ float unflip(unsigned k) {
    unsigned u = k & 0xFFFFF800u;
    u ^= (u & 0x80000000u) ? 0x80000000u : 0xFFFFFFFFu;
    return __uint_as_float(u);
}

// ---- cross-lane helpers: DPP for offsets inside a 16-lane row, bpermute beyond ----
template<int C>
__device__ __forceinline__ unsigned dppu(unsigned v) {
    return (unsigned)__builtin_amdgcn_update_dpp(0, (int)v, C, 0xF, 0xF, true);
}
template<int OFF>
__device__ __forceinline__ unsigned shx(unsigned v) {
    if constexpr (OFF == 1)       return dppu<0xB1>(v);    // quad_perm xor 1
    else if constexpr (OFF == 2)  return dppu<0x4E>(v);    // quad_perm xor 2
    else if constexpr (OFF == 7)  return dppu<0x141>(v);   // row_half_mirror = xor 7
    else if constexpr (OFF == 15) return dppu<0x140>(v);   // row_mirror      = xor 15
    else return (unsigned)__shfl_xor((int)v, OFF, 64);
}
template<int C>
__device__ __forceinline__ double dppd(double v) {
    unsigned long long u = (unsigned long long)__double_as_longlong(v);
    int lo = __builtin_amdgcn_update_dpp(0, (int)(u & 0xffffffffull), C, 0xF, 0xF, true);
    int hi = __builtin_amdgcn_update_dpp(0, (int)(u >> 32),           C, 0xF, 0xF, true);
    return __longlong_as_double((long long)(((unsigned long long)(unsigned)hi << 32) | (unsigned)lo));
}

// ascending bitonic cleanup of a bitonic 16-sequence (j = 8,4,2,1)
__device__ __forceinline__ void clean16(unsigned k[CAND]) {
#define CMPEX(a_, b_) { unsigned lo = k[a_] < k[b_] ? k[a_] : k[b_]; \
                        unsigned hi = k[a_] < k[b_] ? k[b_] : k[a_]; k[a_] = lo; k[b_] = hi; }
    CMPEX(0,8) CMPEX(1,9) CMPEX(2,10) CMPEX(3,11) CMPEX(4,12) CMPEX(5,13) CMPEX(6,14) CMPEX(7,15)
    CMPEX(0,4) CMPEX(1,5) CMPEX(2,6)  CMPEX(3,7)  CMPEX(8,12) CMPEX(9,13) CMPEX(10,14) CMPEX(11,15)
    CMPEX(0,2) CMPEX(1,3) CMPEX(4,6)  CMPEX(5,7)  CMPEX(8,10) CMPEX(9,11) CMPEX(12,14) CMPEX(13,15)
    CMPEX(0,1) CMPEX(2,3) CMPEX(4,5)  CMPEX(6,7)  CMPEX(8,9)  CMPEX(10,11) CMPEX(12,13) CMPEX(14,15)
#undef CMPEX
}

// one butterfly merge step: my sorted-16 vs partner's sorted-16 -> top-16 of union, sorted
template<int OFF>
__device__ __forceinline__ void merge16(unsigned k[CAND]) {
    unsigned pk[CAND];
#pragma unroll
    for (int j = 0; j < CAND; ++j) pk[j] = shx<OFF>(k[j]);
#pragma unroll
    for (int j = 0; j < CAND; ++j) {
        unsigned b2_ = pk[CAND - 1 - j];
        k[j] = (k[j] < b2_) ? k[j] : b2_;
    }
    clean16(k);
}

// xx[b,n] = sum_c x[b,c,n]^2  (fp32 proxy only — phase 2 rescores exactly when needed)
__global__ __launch_bounds__(256) void compute_xx(const float* __restrict__ x,
                                                  float* __restrict__ xx) {
    int t = blockIdx.x * 256 + threadIdx.x;      // t in [0, B*N)
    int b = t >> 11, n = t & (NN - 1);
    const float* xb = x + b * (CC * NN) + n;
    float s = 0.f;
#pragma unroll
    for (int c = 0; c < CC; ++c) { float v = xb[c * NN]; s = fmaf(v, v, s); }
    xx[t] = s;
}

// R13 baseline + sched_group_barrier-forced pipeline in phase A.
// R14 (manual rotation), R15 (launch-bounds+unroll), R16 (parity buffers) all failed
// to unstick the compiler's load-then-use schedule (VGPR ~44-52, VALUBusy ~49%,
// per-c duty ~32/230 cyc). The group-barrier pattern [3 VMEM-read][16 VALU] per
// unrolled iteration forces each VALU group to consume the PREVIOUS group's loads
// (only data-ready ops can fill the quota) -> 1-deep pipeline, no extra v_movs.
__global__ __launch_bounds__(NT, 4) void knn_upsample(const float* __restrict__ x,
                                                      const float* __restrict__ xxg,
                                                      float* __restrict__ out) {
    __shared__ unsigned keys[QB][NN];   // 32 KB

    const int tid  = threadIdx.x;
    const int w    = tid >> 6;                 // wave id = query id within block
    const int lane = tid & 63;
    const int blk  = blockIdx.x;

    // XCD-aware batch affinity (R13, measured: HBM fetch 38 MB -> 4.5 MB per dispatch)
    const int xcd = blk & 7;
    const int j   = blk >> 3;                  // [0, 1024)
    const int b   = 2 * xcd + (j >> 9);        // batch
    const int n0  = (j & 511) << 2;            // 4 consecutive queries per block
    const float* xb = x + b * (CC * NN);

    // ---------------- phase A: inner products; wave w covers 512 m-points for ALL 4 queries ----------------
    const int mbase = w * MPW + 4 * lane;      // points mbase..mbase+3 and mbase+256..+259
    floatx2 acc[QB][4];                        // [query][pt-pair]
#pragma unroll
    for (int q2 = 0; q2 < QB; ++q2)
#pragma unroll
        for (int g = 0; g < 4; ++g) acc[q2][g] = (floatx2){0.f, 0.f};

#pragma unroll
    for (int c = 0; c < CC; ++c) {
        const float4 xv0 = *(const float4*)(xb + c * NN + mbase);
        const float4 xv1 = *(const float4*)(xb + c * NN + mbase + 256);
        const float4 qa  = *(const float4*)(xb + c * NN + n0);   // 4 queries (block-uniform)
        const floatx2 x0 = {xv0.x, xv0.y}, x1 = {xv0.z, xv0.w};
        const floatx2 x2 = {xv1.x, xv1.y}, x3 = {xv1.z, xv1.w};
        const float qv[QB] = {qa.x, qa.y, qa.z, qa.w};
#pragma unroll
        for (int q2 = 0; q2 < QB; ++q2) {
            const floatx2 qq = {qv[q2], qv[q2]};
            acc[q2][0] = x0 * qq + acc[q2][0];   // v_pk_fma_f32
            acc[q2][1] = x1 * qq + acc[q2][1];
            acc[q2][2] = x2 * qq + acc[q2][2];
            acc[q2][3] = x3 * qq + acc[q2][3];
        }
        // scheduling directive (no code): alternate 3 VMEM-reads with 16 VALU ops.
        // Legal fills for each VALU quota are only FMAs whose loads already issued
        // -> forces loads one group ahead (software pipeline) without v_mov copies.
        __builtin_amdgcn_sched_group_barrier(0x020, 3, 0);   // 3 VMEM read
        __builtin_amdgcn_sched_group_barrier(0x002, 16, 0);  // 16 VALU
    }

    // epilogue: r = xx_m - 2*I -> packed u32 key (idx in low 11 bits) -> LDS
    {
        const float4 xxv0 = *(const float4*)(xxg + b * NN + mbase);
        const float4 xxv1 = *(const float4*)(xxg + b * NN + mbase + 256);
        const float xxa[8] = {xxv0.x, xxv0.y, xxv0.z, xxv0.w, xxv1.x, xxv1.y, xxv1.z, xxv1.w};
#pragma unroll
        for (int q2 = 0; q2 < QB; ++q2) {
            const int nq = n0 + q2;
            unsigned kk[8];
#pragma unroll
            for (int p = 0; p < 8; ++p) {
                const int g = p >> 1;
                float I = (p & 1) ? acc[q2][g].y : acc[q2][g].x;
                float r = fmaf(-2.f, I, xxa[p]);
                const int m = mbase + ((p < 4) ? p : (252 + p));   // +0..3 or +256..259
                unsigned key = (ordflip(r) & 0xFFFFF800u) | (unsigned)m;
                kk[p] = (m == nq) ? 0xFFFFFFFFu : key;             // exclude self
            }
            *(uint4*)(&keys[q2][mbase])       = make_uint4(kk[0], kk[1], kk[2], kk[3]);
            *(uint4*)(&keys[q2][mbase + 256]) = make_uint4(kk[4], kk[5], kk[6], kk[7]);
        }
    }
    __syncthreads();

    // ---------------- phase B: wave w selects candidates for query n = n0 + w ----------------
    const int n = n0 + w;
    unsigned key[DPL];
#pragma unroll
    for (int t = 0; t < 8; ++t) {              // contiguous uint4 reads (ds_read_b128)
        uint4 kv = *(const uint4*)(&keys[w][256 * t + 4 * lane]);
        key[4 * t] = kv.x; key[4 * t + 1] = kv.y; key[4 * t + 2] = kv.z; key[4 * t + 3] = kv.w;
    }

    // per-lane TOP-8-of-32: 4 bitonic sort-8 (asc,desc,asc,desc), discard-merge pairs,
    // final discard-merge. P(lane holds >8 of wave top-16) ~ 4e-11/query — safe.
#pragma unroll
    for (int blk4 = 0; blk4 < 4; ++blk4) {
        const int base = blk4 * 8;
        const bool asc = (blk4 & 1) == 0;
#pragma unroll
        for (int k = 2; k <= 8; k <<= 1) {
#pragma unroll
            for (int jj = k >> 1; jj > 0; jj >>= 1) {
#pragma unroll
                for (int i = 0; i < 8; ++i) {
                    int l = i ^ jj;
                    if (l > i) {
                        bool up = (((i & k) == 0) == asc);
                        unsigned a = key[base + i], b2_ = key[base + l];
                        unsigned lo = a < b2_ ? a : b2_, hi = a < b2_ ? b2_ : a;
                        key[base + i] = up ? lo : hi;
                        key[base + l] = up ? hi : lo;
                    }
                }
            }
        }
    }
#pragma unroll
    for (int i = 0; i < 8; ++i) key[i] = key[i] < key[8 + i] ? key[i] : key[8 + i];
#pragma unroll
    for (int jj = 4; jj > 0; jj >>= 1)
#pragma unroll
        for (int i = 0; i < 8; ++i) {
            int l = i ^ jj;
            if (l > i && key[l] < key[i]) { unsigned t2 = key[i]; key[i] = key[l]; key[l] = t2; }
        }
#pragma unroll
    for (int i = 0; i < 8; ++i) key[16 + i] = key[16 + i] < key[24 + i] ? key[16 + i] : key[24 + i];
#pragma unroll
    for (int jj = 4; jj > 0; jj >>= 1)
#pragma unroll
        for (int i = 0; i < 8; ++i) {
            int l = i ^ jj;
            if (l > i && key[16 + l] < key[16 + i]) { unsigned t2 = key[16 + i]; key[16 + i] = key[16 + l]; key[16 + l] = t2; }
        }
#pragma unroll
    for (int i = 0; i < 8; ++i) key[i] = key[i] < key[16 + 7 - i] ? key[i] : key[16 + 7 - i];
#pragma unroll
    for (int jj = 4; jj > 0; jj >>= 1)
#pragma unroll
        for (int i = 0; i < 8; ++i) {
            int l = i ^ jj;
            if (l > i && key[l] < key[i]) { unsigned t2 = key[i]; key[i] = key[l]; key[l] = t2; }
        }

    // butterfly step 1 (xor 1, DPP): my-8 ++ reversed partner-8 = bitonic 16 -> sorted 16
    unsigned k16[CAND];
    {
        unsigned p8[8];
#pragma unroll
        for (int jj = 0; jj < 8; ++jj) p8[jj] = shx<1>(key[jj]);
#pragma unroll
        for (int jj = 0; jj < 8; ++jj) { k16[jj] = key[jj]; k16[8 + jj] = p8[7 - jj]; }
        clean16(k16);
    }
    merge16<2>(k16);
    merge16<7>(k16);
    merge16<15>(k16);
    merge16<16>(k16);
    merge16<32>(k16);

    // extract indices; belt-and-braces lane-0 broadcast (unique keys guarantee uniformity)
    int i16[CAND];
#pragma unroll
    for (int jj = 0; jj < CAND; ++jj) i16[jj] = __shfl((int)(k16[jj] & 0x7FFu), 0, 64);

    // ---------------- gap test: can the proxy alone certify the top-8 SET? ----------------
    const float r7 = unflip(k16[7]), r8 = unflip(k16[8]);
    const float eps = fmaxf(fabsf(r7), fabsf(r8)) * 0.0009765625f + 2e-3f;  // 2^-10 rel + abs floor
    float ssum = 0.f;

    if (r8 - r7 > eps) {
        // ---- fast path: proxy top-8 is exact; 8 gathers + sum ----
#pragma unroll
        for (int jj = 0; jj < KK; ++jj) ssum += xb[lane * NN + i16[jj]];
    } else {
        // ---- slow path: exact fp64 rescore -> u64 keys -> pairwise rank ----
        const double qd = (double)xb[lane * NN + n];   // lane = channel
        u64 ke[CAND];
        float xf[CAND];
#pragma unroll
        for (int jj = 0; jj < CAND; ++jj) {
            const float xv = xb[lane * NN + i16[jj]];
            xf[jj] = xv;
            double dt = (double)xv - qd;
            double part = dt * dt;
            part += dppd<0xB1>(part);
            part += dppd<0x4E>(part);
            part += dppd<0x141>(part);
            part += dppd<0x140>(part);
            part += __shfl_xor(part, 16, 64);
            part += __shfl_xor(part, 32, 64);
            u64 eb = (u64)__double_as_longlong(part);  // identical on all lanes, >= 0
            ke[jj] = (eb & ~2047ull) | (u64)(unsigned)i16[jj];
        }
        int rank[CAND];
#pragma unroll
        for (int jj = 0; jj < CAND; ++jj) rank[jj] = 0;
#pragma unroll
        for (int jj = 0; jj < CAND; ++jj)
#pragma unroll
            for (int k2 = jj + 1; k2 < CAND; ++k2) {
                const bool jw = ke[jj] < ke[k2];
                rank[k2] += jw ? 1 : 0;
                rank[jj] += jw ? 0 : 1;
            }
#pragma unroll
        for (int jj = 0; jj < CAND; ++jj) ssum += (rank[jj] < KK) ? xf[jj] : 0.f;
    }

    float mean = ssum * 0.125f;
    float* ob = out + b * (CC * 2 * NN) + lane * (2 * NN);
    ob[n]      = xb[lane * NN + n];   // first half: copy of x
    ob[NN + n] = mean;                // second half: mean of exact 8-NN features
}

extern "C" void kernel_launch(void* const* d_in, const int* in_sizes, int n_in,
                              void* d_out, int out_size, void* d_ws, size_t ws_size,
                              hipStream_t stream) {
    (void)in_sizes; (void)n_in; (void)ws_size; (void)out_size;
    const float* x = (const float*)d_in[0];
    float* xx = (float*)d_ws;                 // B*N floats = 128 KB scratch
    float* out = (float*)d_out;
    compute_xx<<<dim3(BB * NN / 256), dim3(256), 0, stream>>>(x, xx);
    knn_upsample<<<dim3(BB * NN / QB), dim3(NT), 0, stream>>>(x, xx, out);
}

// Round 18
// 259.720 us; speedup vs baseline: 1.1840x; 1.1799x over previous
//
#include <hip/hip_runtime.h>
#include <math.h>

#define BB 16
#define CC 64
#define NN 2048
#define KK 8
#define CAND 16          // phase-1 candidates (exact top-8 subset; validated R3/R6/R7/R10-R17)
#define QB 8             // queries per block (one per wave); keys LDS = QB*NN*4 = 64 KB
#define NT (QB * 64)     // 512 threads
#define MPW (NN / QB)    // 256 m-points per wave
#define DPL 32           // keys per lane

typedef float floatx2 __attribute__((ext_vector_type(2)));
typedef unsigned long long u64;

// order-preserving fp32 -> u32 flip: ascending uint == ascending float
__device__ __forceinline__ unsigned ordflip(float f) {
    unsigned u = __float_as_uint(f);
    return u ^ ((u & 0x80000000u) ? 0xFFFFFFFFu : 0x80000000u);
}
// inverse (on the masked high bits): recover approximate r from a packed key
__device__ __forceinline__ float unflip(unsigned k) {
    unsigned u = k & 0xFFFFF800u;
    u ^= (u & 0x80000000u) ? 0x80000000u : 0xFFFFFFFFu;
    return __uint_as_float(u);
}

// ---- cross-lane helpers: DPP for offsets inside a 16-lane row, bpermute beyond ----
template<int C>
__device__ __forceinline__ unsigned dppu(unsigned v) {
    return (unsigned)__builtin_amdgcn_update_dpp(0, (int)v, C, 0xF, 0xF, true);
}
template<int OFF>
__device__ __forceinline__ unsigned shx(unsigned v) {
    if constexpr (OFF == 1)       return dppu<0xB1>(v);    // quad_perm xor 1
    else if constexpr (OFF == 2)  return dppu<0x4E>(v);    // quad_perm xor 2
    else if constexpr (OFF == 7)  return dppu<0x141>(v);   // row_half_mirror = xor 7
    else if constexpr (OFF == 15) return dppu<0x140>(v);   // row_mirror      = xor 15
    else return (unsigned)__shfl_xor((int)v, OFF, 64);
}
template<int C>
__device__ __forceinline__ double dppd(double v) {
    unsigned long long u = (unsigned long long)__double_as_longlong(v);
    int lo = __builtin_amdgcn_update_dpp(0, (int)(u & 0xffffffffull), C, 0xF, 0xF, true);
    int hi = __builtin_amdgcn_update_dpp(0, (int)(u >> 32),           C, 0xF, 0xF, true);
    return __longlong_as_double((long long)(((unsigned long long)(unsigned)hi << 32) | (unsigned)lo));
}

// ascending bitonic cleanup of a bitonic 16-sequence (j = 8,4,2,1)
__device__ __forceinline__ void clean16(unsigned k[CAND]) {
#define CMPEX(a_, b_) { unsigned lo = k[a_] < k[b_] ? k[a_] : k[b_]; \
                        unsigned hi = k[a_] < k[b_] ? k[b_] : k[a_]; k[a_] = lo; k[b_] = hi; }
    CMPEX(0,8) CMPEX(1,9) CMPEX(2,10) CMPEX(3,11) CMPEX(4,12) CMPEX(5,13) CMPEX(6,14) CMPEX(7,15)
    CMPEX(0,4) CMPEX(1,5) CMPEX(2,6)  CMPEX(3,7)  CMPEX(8,12) CMPEX(9,13) CMPEX(10,14) CMPEX(11,15)
    CMPEX(0,2) CMPEX(1,3) CMPEX(4,6)  CMPEX(5,7)  CMPEX(8,10) CMPEX(9,11) CMPEX(12,14) CMPEX(13,15)
    CMPEX(0,1) CMPEX(2,3) CMPEX(4,5)  CMPEX(6,7)  CMPEX(8,9)  CMPEX(10,11) CMPEX(12,13) CMPEX(14,15)
#undef CMPEX
}

// one butterfly merge step: my sorted-16 vs partner's sorted-16 -> top-16 of union, sorted
template<int OFF>
__device__ __forceinline__ void merge16(unsigned k[CAND]) {
    unsigned pk[CAND];
#pragma unroll
    for (int j = 0; j < CAND; ++j) pk[j] = shx<OFF>(k[j]);
#pragma unroll
    for (int j = 0; j < CAND; ++j) {
        unsigned b2_ = pk[CAND - 1 - j];
        k[j] = (k[j] < b2_) ? k[j] : b2_;
    }
    clean16(k);
}

// xx[b,n] = sum_c x[b,c,n]^2  (fp32 proxy only — phase 2 rescores exactly when needed)
__global__ __launch_bounds__(256) void compute_xx(const float* __restrict__ x,
                                                  float* __restrict__ xx) {
    int t = blockIdx.x * 256 + threadIdx.x;      // t in [0, B*N)
    int b = t >> 11, n = t & (NN - 1);
    const float* xb = x + b * (CC * NN) + n;
    float s = 0.f;
#pragma unroll
    for (int c = 0; c < CC; ++c) { float v = xb[c * NN]; s = fmaf(v, v, s); }
    xx[t] = s;
}

// QB=8 topology (R11-validated): each block still covers the whole 2048-point slice,
// but there are 256 blocks/batch instead of 512 -> L2 x-read traffic HALVES
// (4.3 GB -> 2.1 GB, ~125 -> ~62 us of L2 service at 34.5 TB/s). Per-wave instr mix
// is identical to QB=4 (3 loads + 16 pk_fma per c). R14-R17 proved the load schedule
// itself is compiler-fixed; this attacks the L2-bandwidth half of the stall instead.
__global__ __launch_bounds__(NT, 2) void knn_upsample(const float* __restrict__ x,
                                                      const float* __restrict__ xxg,
                                                      float* __restrict__ out) {
    __shared__ unsigned keys[QB][NN];   // 64 KB

    const int tid  = threadIdx.x;
    const int w    = tid >> 6;                 // wave id = query id within block
    const int lane = tid & 63;
    const int blk  = blockIdx.x;

    // XCD-aware batch affinity (R13, measured: HBM fetch 38 MB -> 4.5 MB/dispatch):
    // 4096 blocks round-robin to 8 XCDs; pin XCD x to batches {2x, 2x+1}.
    const int xcd = blk & 7;
    const int j   = blk >> 3;                  // [0, 512)
    const int b   = 2 * xcd + (j >> 8);        // batch
    const int n0  = (j & 255) << 3;            // 8 consecutive queries per block
    const float* xb = x + b * (CC * NN);

    // ---------------- phase A (R11-verbatim): wave w covers 256 m-points for ALL 8 queries ----------------
    const int mbase = w * MPW + 4 * lane;      // 4 consecutive m-points per lane
    floatx2 accL[QB], accH[QB];                // acc[q] over (m0,m1) and (m2,m3)
#pragma unroll
    for (int q2 = 0; q2 < QB; ++q2) { accL[q2] = (floatx2){0.f, 0.f}; accH[q2] = (floatx2){0.f, 0.f}; }

#pragma unroll 8
    for (int c = 0; c < CC; ++c) {
        const float4 xv  = *(const float4*)(xb + c * NN + mbase);         // own 4 m-points
        const float4 qa  = *(const float4*)(xb + c * NN + n0);            // queries 0..3 (block-uniform)
        const float4 qb4 = *(const float4*)(xb + c * NN + n0 + 4);        // queries 4..7
        const floatx2 xlo = {xv.x, xv.y};
        const floatx2 xhi = {xv.z, xv.w};
        const float qv[QB] = {qa.x, qa.y, qa.z, qa.w, qb4.x, qb4.y, qb4.z, qb4.w};
#pragma unroll
        for (int q2 = 0; q2 < QB; ++q2) {
            const floatx2 qq = {qv[q2], qv[q2]};
            accL[q2] = xlo * qq + accL[q2];    // v_pk_fma_f32
            accH[q2] = xhi * qq + accH[q2];
        }
    }

    // epilogue: r = xx_m - 2*I -> packed u32 key (idx in low 11 bits) -> LDS
    {
        const float4 xxv = *(const float4*)(xxg + b * NN + mbase);
        const float xxa[4] = {xxv.x, xxv.y, xxv.z, xxv.w};
#pragma unroll
        for (int q2 = 0; q2 < QB; ++q2) {
            const int nq = n0 + q2;
            unsigned kk[4];
#pragma unroll
            for (int p = 0; p < 4; ++p) {
                float I = (p < 2) ? ((p == 0) ? accL[q2].x : accL[q2].y)
                                  : ((p == 2) ? accH[q2].x : accH[q2].y);
                float r = fmaf(-2.f, I, xxa[p]);
                unsigned key = (ordflip(r) & 0xFFFFF800u) | (unsigned)(mbase + p);
                kk[p] = (mbase + p == nq) ? 0xFFFFFFFFu : key;   // exclude self
            }
            *(uint4*)(&keys[q2][mbase]) = make_uint4(kk[0], kk[1], kk[2], kk[3]);
        }
    }
    __syncthreads();

    // ---------------- phase B (R12-verbatim): wave w selects candidates for query n = n0 + w ----------------
    const int n = n0 + w;
    unsigned key[DPL];
#pragma unroll
    for (int t = 0; t < 8; ++t) {              // contiguous uint4 reads (ds_read_b128)
        uint4 kv = *(const uint4*)(&keys[w][256 * t + 4 * lane]);
        key[4 * t] = kv.x; key[4 * t + 1] = kv.y; key[4 * t + 2] = kv.z; key[4 * t + 3] = kv.w;
    }

    // per-lane TOP-8-of-32: 4 bitonic sort-8 (asc,desc,asc,desc), discard-merge pairs,
    // final discard-merge. P(lane holds >8 of wave top-16) ~ 4e-11/query — safe.
#pragma unroll
    for (int blk4 = 0; blk4 < 4; ++blk4) {
        const int base = blk4 * 8;
        const bool asc = (blk4 & 1) == 0;
#pragma unroll
        for (int k = 2; k <= 8; k <<= 1) {
#pragma unroll
            for (int jj = k >> 1; jj > 0; jj >>= 1) {
#pragma unroll
                for (int i = 0; i < 8; ++i) {
                    int l = i ^ jj;
                    if (l > i) {
                        bool up = (((i & k) == 0) == asc);
                        unsigned a = key[base + i], b2_ = key[base + l];
                        unsigned lo = a < b2_ ? a : b2_, hi = a < b2_ ? b2_ : a;
                        key[base + i] = up ? lo : hi;
                        key[base + l] = up ? hi : lo;
                    }
                }
            }
        }
    }
#pragma unroll
    for (int i = 0; i < 8; ++i) key[i] = key[i] < key[8 + i] ? key[i] : key[8 + i];
#pragma unroll
    for (int jj = 4; jj > 0; jj >>= 1)
#pragma unroll
        for (int i = 0; i < 8; ++i) {
            int l = i ^ jj;
            if (l > i && key[l] < key[i]) { unsigned t2 = key[i]; key[i] = key[l]; key[l] = t2; }
        }
#pragma unroll
    for (int i = 0; i < 8; ++i) key[16 + i] = key[16 + i] < key[24 + i] ? key[16 + i] : key[24 + i];
#pragma unroll
    for (int jj = 4; jj > 0; jj >>= 1)
#pragma unroll
        for (int i = 0; i < 8; ++i) {
            int l = i ^ jj;
            if (l > i && key[16 + l] < key[16 + i]) { unsigned t2 = key[16 + i]; key[16 + i] = key[16 + l]; key[16 + l] = t2; }
        }
#pragma unroll
    for (int i = 0; i < 8; ++i) key[i] = key[i] < key[16 + 7 - i] ? key[i] : key[16 + 7 - i];
#pragma unroll
    for (int jj = 4; jj > 0; jj >>= 1)
#pragma unroll
        for (int i = 0; i < 8; ++i) {
            int l = i ^ jj;
            if (l > i && key[l] < key[i]) { unsigned t2 = key[i]; key[i] = key[l]; key[l] = t2; }
        }

    // butterfly step 1 (xor 1, DPP): my-8 ++ reversed partner-8 = bitonic 16 -> sorted 16
    unsigned k16[CAND];
    {
        unsigned p8[8];
#pragma unroll
        for (int jj = 0; jj < 8; ++jj) p8[jj] = shx<1>(key[jj]);
#pragma unroll
        for (int jj = 0; jj < 8; ++jj) { k16[jj] = key[jj]; k16[8 + jj] = p8[7 - jj]; }
        clean16(k16);
    }
    merge16<2>(k16);
    merge16<7>(k16);
    merge16<15>(k16);
    merge16<16>(k16);
    merge16<32>(k16);

    // extract indices; belt-and-braces lane-0 broadcast (unique keys guarantee uniformity)
    int i16[CAND];
#pragma unroll
    for (int jj = 0; jj < CAND; ++jj) i16[jj] = __shfl((int)(k16[jj] & 0x7FFu), 0, 64);

    // ---------------- gap test: can the proxy alone certify the top-8 SET? ----------------
    const float r7 = unflip(k16[7]), r8 = unflip(k16[8]);
    const float eps = fmaxf(fabsf(r7), fabsf(r8)) * 0.0009765625f + 2e-3f;  // 2^-10 rel + abs floor
    float ssum = 0.f;

    if (r8 - r7 > eps) {
        // ---- fast path: proxy top-8 is exact; 8 gathers + sum ----
#pragma unroll
        for (int jj = 0; jj < KK; ++jj) ssum += xb[lane * NN + i16[jj]];
    } else {
        // ---- slow path: exact fp64 rescore -> u64 keys -> pairwise rank ----
        const double qd = (double)xb[lane * NN + n];   // lane = channel
        u64 ke[CAND];
        float xf[CAND];
#pragma unroll
        for (int jj = 0; jj < CAND; ++jj) {
            const float xv = xb[lane * NN + i16[jj]];
            xf[jj] = xv;
            double dt = (double)xv - qd;
            double part = dt * dt;
            part += dppd<0xB1>(part);
            part += dppd<0x4E>(part);
            part += dppd<0x141>(part);
            part += dppd<0x140>(part);
            part += __shfl_xor(part, 16, 64);
            part += __shfl_xor(part, 32, 64);
            u64 eb = (u64)__double_as_longlong(part);  // identical on all lanes, >= 0
            ke[jj] = (eb & ~2047ull) | (u64)(unsigned)i16[jj];
        }
        int rank[CAND];
#pragma unroll
        for (int jj = 0; jj < CAND; ++jj) rank[jj] = 0;
#pragma unroll
        for (int jj = 0; jj < CAND; ++jj)
#pragma unroll
            for (int k2 = jj + 1; k2 < CAND; ++k2) {
                const bool jw = ke[jj] < ke[k2];
                rank[k2] += jw ? 1 : 0;
                rank[jj] += jw ? 0 : 1;
            }
#pragma unroll
        for (int jj = 0; jj < CAND; ++jj) ssum += (rank[jj] < KK) ? xf[jj] : 0.f;
    }

    float mean = ssum * 0.125f;
    float* ob = out + b * (CC * 2 * NN) + lane * (2 * NN);
    ob[n]      = xb[lane * NN + n];   // first half: copy of x
    ob[NN + n] = mean;                // second half: mean of exact 8-NN features
}

extern "C" void kernel_launch(void* const* d_in, const int* in_sizes, int n_in,
                              void* d_out, int out_size, void* d_ws, size_t ws_size,
                              hipStream_t stream) {
    (void)in_sizes; (void)n_in; (void)ws_size; (void)out_size;
    const float* x = (const float*)d_in[0];
    float* xx = (float*)d_ws;                 // B*N floats = 128 KB scratch
    float* out = (float*)d_out;
    compute_xx<<<dim3(BB * NN / 256), dim3(256), 0, stream>>>(x, xx);
    knn_upsample<<<dim3(BB * NN / QB), dim3(NT), 0, stream>>>(x, xx, out);
}